// Round 6
// baseline (85.470 us; speedup 1.0000x reference)
//
#include <hip/hip_runtime.h>

#define NB 32768
#define NN 12
#define DD 64
#define OBSD 28
#define EPB 16            // batch elements per wave (one MFMA N-tile)
#define NSLOT 136         // weight-fragment slots in d_ws

typedef __bf16 bf16x8 __attribute__((ext_vector_type(8)));
typedef __bf16 bf16x4 __attribute__((ext_vector_type(4)));
typedef float  f32x4  __attribute__((ext_vector_type(4)));

#define MFMA(a, b, c) __builtin_amdgcn_mfma_f32_16x16x32_bf16((a), (b), (c), 0, 0, 0)

__device__ __forceinline__ float tanh_fast(float x) {
    float e = __builtin_amdgcn_exp2f(x * 2.885390081777927f);
    float r = __builtin_amdgcn_rcpf(e + 1.f);
    return __builtin_fmaf(-2.f, r, 1.f);
}

__device__ __forceinline__ f32x4 ld4(const float* p) { return *(const f32x4*)p; }

// adjacency sparsity (12 nodes, 11 edges + self loops = 34 nonzeros), grouped by output node
static constexpr int AC_OFF[13] = {0,5,8,11,13,16,19,21,24,27,29,32,34};
static constexpr int AC_M[34] = {0,1,4,7,10, 0,1,2, 1,2,3, 2,3, 0,4,5, 4,5,6, 5,6, 0,7,8, 7,8,9, 8,9, 0,10,11, 10,11};
static constexpr int AC_N[34] = {0,0,0,0,0, 1,1,1, 2,2,2, 3,3, 4,4,4, 5,5,5, 6,6, 7,7,7, 8,8,8, 9,9, 10,10,10, 11,11};

// ---------------------------------------------------------------------------
// prep: pack W^T into MFMA A-fragment layout, bf16, into d_ws. (unchanged)
// slot map: 0..31 gcn {gp1,gp2,gv1,gv2}: mat*8 + w*2 + ks
//           32..39 pol1: 32 + w*2 + ks
//           40..135 val1: 40 + w*24 + (n*2+h)
// per (slot, lane): 8 bf16 = A[w*16 + (l&15)][ks*32 + (l>>4)*8 + i] = W[k][dout]
// ---------------------------------------------------------------------------
__global__ __launch_bounds__(256) void prep_weights(
    const float* __restrict__ gp1, const float* __restrict__ gp2,
    const float* __restrict__ gv1, const float* __restrict__ gv2,
    const float* __restrict__ pol1, const float* __restrict__ val1,
    __bf16* __restrict__ wsb)
{
    int gid = blockIdx.x * blockDim.x + threadIdx.x;
    if (gid >= NSLOT * 64) return;
    int slot = gid >> 6, l = gid & 63;
    const float* W; int w, ks;
    if (slot < 32) {
        int m = slot >> 3;
        W = (m == 0) ? gp1 : (m == 1) ? gp2 : (m == 2) ? gv1 : gv2;
        w = (slot >> 1) & 3; ks = slot & 1;
    } else if (slot < 40) {
        W = pol1; w = (slot - 32) >> 1; ks = slot & 1;
    } else {
        int idx = slot - 40; W = val1; w = idx / 24; ks = idx % 24;
    }
    int dout = w * 16 + (l & 15);
    int k0 = ks * 32 + (l >> 4) * 8;
    bf16x8 v;
    #pragma unroll
    for (int i = 0; i < 8; ++i) v[i] = (__bf16)W[(size_t)(k0 + i) * 64 + dout];
    *(bf16x8*)(wsb + (size_t)gid * 8) = v;
}

// ---------------------------------------------------------------------------
// main kernel: 64 threads = 1 wave per (16-el tile, branch). Zero barriers.
// Activations live as B-frags in registers; per-layer feat-regroup goes
// through a 12KB wave-private LDS bounce (in-order DS, no syncthreads).
// ---------------------------------------------------------------------------
__global__ __launch_bounds__(64, 2) void nervenet_wave(
    const float* __restrict__ obs, const float* __restrict__ adjn,
    const float* __restrict__ w_in_t, const float* __restrict__ b_in_t,
    const float* __restrict__ w_in_j, const float* __restrict__ b_in_j,
    const float* __restrict__ b_gp1, const float* __restrict__ b_gp2,
    const float* __restrict__ b_gv1, const float* __restrict__ b_gv2,
    const float* __restrict__ b_pol1, const float* __restrict__ w_pol2, const float* __restrict__ b_pol2,
    const float* __restrict__ b_val1, const float* __restrict__ w_val2, const float* __restrict__ b_val2,
    const __bf16* __restrict__ wsb, float* __restrict__ out)
{
    // bounce[region][node][el][16 feats * 2B]; region r holds w-slice (w&1)
    __shared__ __align__(16) unsigned char bounce[2][NN][EPB][32];   // 12288 B

    const int l  = threadIdx.x;
    const int el = l & 15;
    const int kg = l >> 4;
    const bool isP = (blockIdx.x & 1) == 0;
    const int b0 = (int)(blockIdx.x >> 1) * EPB;
    const int fA = kg * 8, fB = 32 + kg * 8;   // this lane's frag feats (ks0 / ks1)

    // adjacency coefficients: uniform addr + literal idx -> scalar loads
    float ac[34];
    #pragma unroll
    for (int i = 0; i < 34; ++i) ac[i] = adjn[AC_N[i] * 12 + AC_M[i]];

    bf16x8 xf[NN][2];   // activations as MFMA B-fragments, 96 VGPR

    // ---- embed: lane computes its own 16 frag-feats for all 12 nodes ----
    {
        float ov[28];
        {
            const f32x4* os4 = (const f32x4*)(obs + (size_t)(b0 + el) * OBSD);
            f32x4* ovv = (f32x4*)ov;
            #pragma unroll
            for (int q = 0; q < 7; ++q) ovv[q] = os4[q];
        }
        // torso -> node 0
        f32x4 ya = ld4(b_in_t + fA), yb = ld4(b_in_t + fA + 4);
        f32x4 yc = ld4(b_in_t + fB), yd = ld4(b_in_t + fB + 4);
        #pragma unroll
        for (int t = 0; t < 6; ++t) {
            const float o = ov[t];
            f32x4 wa = ld4(w_in_t + t * DD + fA), wb = ld4(w_in_t + t * DD + fA + 4);
            f32x4 wc = ld4(w_in_t + t * DD + fB), wd = ld4(w_in_t + t * DD + fB + 4);
            #pragma unroll
            for (int r = 0; r < 4; ++r) {
                ya[r] = __builtin_fmaf(o, wa[r], ya[r]);
                yb[r] = __builtin_fmaf(o, wb[r], yb[r]);
                yc[r] = __builtin_fmaf(o, wc[r], yc[r]);
                yd[r] = __builtin_fmaf(o, wd[r], yd[r]);
            }
        }
        #pragma unroll
        for (int r = 0; r < 4; ++r) {
            xf[0][0][r]     = (__bf16)tanh_fast(ya[r]);
            xf[0][0][4 + r] = (__bf16)tanh_fast(yb[r]);
            xf[0][1][r]     = (__bf16)tanh_fast(yc[r]);
            xf[0][1][4 + r] = (__bf16)tanh_fast(yd[r]);
        }
        // joints -> nodes 1..11
        f32x4 wA0 = ld4(w_in_j + fA),      wA1 = ld4(w_in_j + fA + 4);
        f32x4 wA2 = ld4(w_in_j + fB),      wA3 = ld4(w_in_j + fB + 4);
        f32x4 wB0 = ld4(w_in_j + DD + fA), wB1 = ld4(w_in_j + DD + fA + 4);
        f32x4 wB2 = ld4(w_in_j + DD + fB), wB3 = ld4(w_in_j + DD + fB + 4);
        f32x4 bj0 = ld4(b_in_j + fA), bj1 = ld4(b_in_j + fA + 4);
        f32x4 bj2 = ld4(b_in_j + fB), bj3 = ld4(b_in_j + fB + 4);
        #pragma unroll
        for (int n = 1; n < NN; ++n) {
            const float j0 = ov[4 + 2 * n], j1 = ov[5 + 2 * n];
            f32x4 v0, v1, v2, v3;
            #pragma unroll
            for (int r = 0; r < 4; ++r) {
                v0[r] = __builtin_fmaf(j1, wB0[r], __builtin_fmaf(j0, wA0[r], bj0[r]));
                v1[r] = __builtin_fmaf(j1, wB1[r], __builtin_fmaf(j0, wA1[r], bj1[r]));
                v2[r] = __builtin_fmaf(j1, wB2[r], __builtin_fmaf(j0, wA2[r], bj2[r]));
                v3[r] = __builtin_fmaf(j1, wB3[r], __builtin_fmaf(j0, wA3[r], bj3[r]));
            }
            #pragma unroll
            for (int r = 0; r < 4; ++r) {
                xf[n][0][r]     = (__bf16)tanh_fast(v0[r]);
                xf[n][0][4 + r] = (__bf16)tanh_fast(v1[r]);
                xf[n][1][r]     = (__bf16)tanh_fast(v2[r]);
                xf[n][1][4 + r] = (__bf16)tanh_fast(v3[r]);
            }
        }
    }

    auto ldws = [&](int slot) {
        return *(const bf16x8*)(wsb + ((size_t)slot * 64 + l) * 8);
    };

    // one GCN layer, fully in-wave: xf <- tanh(A @ (xf @ W) + bias)
    auto layer = [&](int slotbase, const float* __restrict__ bias) {
        bf16x8 xfN[NN];   // new ks0 frags (old xf still needed for w=2,3)
        #pragma unroll
        for (int w = 0; w < 4; ++w) {
            bf16x8 wf0 = ldws(slotbase + w * 2);
            bf16x8 wf1 = ldws(slotbase + w * 2 + 1);
            f32x4 acc[NN];
            #pragma unroll
            for (int n = 0; n < NN; ++n) {
                f32x4 z = {0.f, 0.f, 0.f, 0.f};
                acc[n] = MFMA(wf1, xf[n][1], MFMA(wf0, xf[n][0], z));
            }
            f32x4 bv = ld4(bias + w * 16 + kg * 4);
            #pragma unroll
            for (int n = 0; n < NN; ++n) {
                f32x4 y = bv;
                #pragma unroll
                for (int j = AC_OFF[n]; j < AC_OFF[n + 1]; ++j) {
                    const float a = ac[j];
                    #pragma unroll
                    for (int r = 0; r < 4; ++r) y[r] = __builtin_fmaf(a, acc[AC_M[j]][r], y[r]);
                }
                bf16x4 o;
                #pragma unroll
                for (int r = 0; r < 4; ++r) o[r] = (__bf16)tanh_fast(y[r]);
                *(bf16x4*)(&bounce[w & 1][n][el][kg * 8]) = o;   // slice write, conflict-free
            }
            if (w == 1) {        // regions 0,1 hold feats 0..31 -> new ks0 frags
                #pragma unroll
                for (int n = 0; n < NN; ++n)
                    xfN[n] = *(const bf16x8*)(&bounce[kg >> 1][n][el][(kg & 1) * 16]);
            }
            if (w == 3) {        // regions 0,1 now hold feats 32..63 -> new ks1 frags
                #pragma unroll
                for (int n = 0; n < NN; ++n)
                    xf[n][1] = *(const bf16x8*)(&bounce[kg >> 1][n][el][(kg & 1) * 16]);
                #pragma unroll
                for (int n = 0; n < NN; ++n) xf[n][0] = xfN[n];
            }
        }
    };

    if (isP) {
        layer(0, b_gp1);
        layer(8, b_gp2);
        // policy head: latent_pi[b][nj] over nodes 1..11
        float pacc[11];
        #pragma unroll
        for (int nj = 0; nj < 11; ++nj) pacc[nj] = 0.f;
        #pragma unroll
        for (int w = 0; w < 4; ++w) {
            bf16x8 pf0 = ldws(32 + w * 2), pf1 = ldws(32 + w * 2 + 1);
            f32x4 bp  = ld4(b_pol1 + w * 16 + kg * 4);
            f32x4 wp2 = ld4(w_pol2 + w * 16 + kg * 4);
            #pragma unroll
            for (int nj = 0; nj < 11; ++nj) {
                f32x4 a = MFMA(pf1, xf[nj + 1][1], MFMA(pf0, xf[nj + 1][0], bp));
                float s = 0.f;
                #pragma unroll
                for (int r = 0; r < 4; ++r) s += tanh_fast(a[r]) * wp2[r];
                pacc[nj] += s;
            }
        }
        const float bp2 = b_pol2[0];
        #pragma unroll
        for (int nj = 0; nj < 11; ++nj) {
            float p = pacc[nj];
            p += __shfl_xor(p, 16);
            p += __shfl_xor(p, 32);
            if (kg == 0) out[(size_t)(b0 + el) * 11 + nj] = p + bp2;
        }
    } else {
        layer(16, b_gv1);
        layer(24, b_gv2);
        // value head: flat xv2 (768) @ w_val1 -> tanh -> @ w_val2
        float vacc = 0.f;
        #pragma unroll
        for (int w = 0; w < 4; ++w) {
            f32x4 a0 = ld4(b_val1 + w * 16 + kg * 4);
            f32x4 a1 = {0.f, 0.f, 0.f, 0.f};
            #pragma unroll
            for (int n = 0; n < NN; n += 2) {
                a0 = MFMA(ldws(40 + w * 24 + n * 2 + 1), xf[n][1],
                     MFMA(ldws(40 + w * 24 + n * 2),     xf[n][0], a0));
                a1 = MFMA(ldws(40 + w * 24 + (n + 1) * 2 + 1), xf[n + 1][1],
                     MFMA(ldws(40 + w * 24 + (n + 1) * 2),     xf[n + 1][0], a1));
            }
            f32x4 wv2 = ld4(w_val2 + w * 16 + kg * 4);
            #pragma unroll
            for (int r = 0; r < 4; ++r) vacc += tanh_fast(a0[r] + a1[r]) * wv2[r];
        }
        vacc += __shfl_xor(vacc, 16);
        vacc += __shfl_xor(vacc, 32);
        if (kg == 0) out[(size_t)NB * 11 + b0 + el] = vacc + b_val2[0];
    }
}

extern "C" void kernel_launch(void* const* d_in, const int* in_sizes, int n_in,
                              void* d_out, int out_size, void* d_ws, size_t ws_size,
                              hipStream_t stream) {
    (void)in_sizes; (void)n_in; (void)out_size; (void)ws_size;
    const float** p = (const float**)d_in;
    __bf16* wsb = (__bf16*)d_ws;
    hipLaunchKernelGGL(prep_weights, dim3(34), dim3(256), 0, stream,
        p[6], p[8], p[10], p[12], p[14], p[18], wsb);
    hipLaunchKernelGGL(nervenet_wave, dim3(2 * (NB / EPB)), dim3(64), 0, stream,
        p[0], p[1], p[2], p[3], p[4], p[5],
        p[7], p[9], p[11], p[13],
        p[15], p[16], p[17],
        p[19], p[20], p[21],
        wsb, (float*)d_out);
}

// Round 7
// 63.196 us; speedup vs baseline: 1.3524x; 1.3524x over previous
//
#include <hip/hip_runtime.h>

#define NB 32768
#define NN 12
#define DD 64
#define OBSD 28
#define EPB 16            // batch elements per block (one MFMA N-tile)
#define NSLOT 136         // weight-fragment slots in d_ws

typedef __bf16 bf16x8 __attribute__((ext_vector_type(8)));
typedef __bf16 bf16x4 __attribute__((ext_vector_type(4)));
typedef __bf16 bf16x2 __attribute__((ext_vector_type(2)));
typedef float  f32x4  __attribute__((ext_vector_type(4)));
typedef float  f32x2  __attribute__((ext_vector_type(2)));

#define MFMA(a, b, c) __builtin_amdgcn_mfma_f32_16x16x32_bf16((a), (b), (c), 0, 0, 0)

__device__ __forceinline__ float tanh_fast(float x) {
    float e = __builtin_amdgcn_exp2f(x * 2.885390081777927f);
    float r = __builtin_amdgcn_rcpf(e + 1.f);
    return __builtin_fmaf(-2.f, r, 1.f);
}

// adjacency sparsity (12 nodes, 11 edges + self loops = 34 nonzeros), grouped by output node
static constexpr int AC_OFF[13] = {0,5,8,11,13,16,19,21,24,27,29,32,34};
static constexpr int AC_M[34] = {0,1,4,7,10, 0,1,2, 1,2,3, 2,3, 0,4,5, 4,5,6, 5,6, 0,7,8, 7,8,9, 8,9, 0,10,11, 10,11};
static constexpr int AC_N[34] = {0,0,0,0,0, 1,1,1, 2,2,2, 3,3, 4,4,4, 5,5,5, 6,6, 7,7,7, 8,8,8, 9,9, 10,10,10, 11,11};

// ---------------------------------------------------------------------------
// prep: pack W^T into MFMA A-fragment layout, bf16, into d_ws. (unchanged)
// ---------------------------------------------------------------------------
__global__ __launch_bounds__(256) void prep_weights(
    const float* __restrict__ gp1, const float* __restrict__ gp2,
    const float* __restrict__ gv1, const float* __restrict__ gv2,
    const float* __restrict__ pol1, const float* __restrict__ val1,
    __bf16* __restrict__ wsb)
{
    int gid = blockIdx.x * blockDim.x + threadIdx.x;
    if (gid >= NSLOT * 64) return;
    int slot = gid >> 6, l = gid & 63;
    const float* W; int w, ks;
    if (slot < 32) {
        int m = slot >> 3;
        W = (m == 0) ? gp1 : (m == 1) ? gp2 : (m == 2) ? gv1 : gv2;
        w = (slot >> 1) & 3; ks = slot & 1;
    } else if (slot < 40) {
        W = pol1; w = (slot - 32) >> 1; ks = slot & 1;
    } else {
        int idx = slot - 40; W = val1; w = idx / 24; ks = idx % 24;
    }
    int dout = w * 16 + (l & 15);
    int k0 = ks * 32 + (l >> 4) * 8;
    bf16x8 v;
    #pragma unroll
    for (int i = 0; i < 8; ++i) v[i] = (__bf16)W[(size_t)(k0 + i) * 64 + dout];
    *(bf16x8*)(wsb + (size_t)gid * 8) = v;
}

// ---------------------------------------------------------------------------
// main kernel: 512 threads = 8 waves. Waves 0-3 = policy branch, 4-7 = value
// branch; balanced R|R, W|W, split-head schedule (round-5 skeleton).
// New: el-major LDS layout (node stride 128B -> ds_write2 merge), packed-f32
// math in mix/embed, layer weight-frags + biases prefetched at kernel start.
// LDS = 2*24576 + 2816 + 256 = 52224 B -> 3 blocks/CU.
// ---------------------------------------------------------------------------
__global__ __launch_bounds__(512, 6) void nervenet_mfma(
    const float* __restrict__ obs, const float* __restrict__ adjn,
    const float* __restrict__ w_in_t, const float* __restrict__ b_in_t,
    const float* __restrict__ w_in_j, const float* __restrict__ b_in_j,
    const float* __restrict__ b_gp1, const float* __restrict__ b_gp2,
    const float* __restrict__ b_gv1, const float* __restrict__ b_gv2,
    const float* __restrict__ b_pol1, const float* __restrict__ w_pol2, const float* __restrict__ b_pol2,
    const float* __restrict__ b_val1, const float* __restrict__ w_val2, const float* __restrict__ b_val2,
    const __bf16* __restrict__ wsb, float* __restrict__ out)
{
    // [el][node][feat] bf16: row = 128 B, node stride 128 B, el stride 1536 B.
    // XOR-swizzle by (el&7)<<4 within each 128-B row (same bank math as before).
    __shared__ unsigned char X [EPB * NN * DD * 2];   // 24576: x -> xv1 -> xv2
    __shared__ unsigned char XP[EPB * NN * DD * 2];   // 24576: xp1 -> xp2
    __shared__ float polp[4 * 11 * EPB];              // 2816 policy partials
    __shared__ float valp[4 * EPB];                   // 256  value partials

    const int tid = threadIdx.x;
    const int l   = tid & 63;
    const int el  = l & 15;
    const int kg  = l >> 4;
    const int wv  = tid >> 6;        // 0..7
    const int w   = wv & 3;          // out-feature tile within branch
    const bool isP = wv < 4;
    const int b0  = blockIdx.x * EPB;
    const int swz = (el & 7) << 4;

    auto ldws = [&](int slot) {
        return *(const bf16x8*)(wsb + ((size_t)slot * 64 + l) * 8);
    };

    // ---- prefetch this wave's layer weight-frags + biases (latency hides under embed) ----
    const int sb1 = isP ? 0 : 16;
    const int sb2 = isP ? 8 : 24;
    const float* bias1 = isP ? b_gp1 : b_gv1;
    const float* bias2 = isP ? b_gp2 : b_gv2;
    bf16x8 wfA0 = ldws(sb1 + w * 2), wfA1 = ldws(sb1 + w * 2 + 1);
    bf16x8 wfB0 = ldws(sb2 + w * 2), wfB1 = ldws(sb2 + w * 2 + 1);
    f32x2 bA0 = *(const f32x2*)(bias1 + w * 16 + kg * 4);
    f32x2 bA1 = *(const f32x2*)(bias1 + w * 16 + kg * 4 + 2);
    f32x2 bB0 = *(const f32x2*)(bias2 + w * 16 + kg * 4);
    f32x2 bB1 = *(const f32x2*)(bias2 + w * 16 + kg * 4 + 2);

    // adjacency coefficients: literal indices + uniform pointer -> scalar loads
    float ac[34];
    #pragma unroll
    for (int i = 0; i < 34; ++i) ac[i] = adjn[AC_N[i] * 12 + AC_M[i]];

    // ---- embed: all 8 waves, thread (ee,fg) computes feats fg*2..fg*2+1, 12 nodes ----
    {
        const int ee = tid & 15, fg = tid >> 4;       // fg 0..31
        const int eswz = (ee & 7) << 4;
        unsigned char* wp = X + (ee * NN) * 128 + ((fg * 4) ^ eswz);
        const float* os = obs + (size_t)(b0 + ee) * OBSD;   // 112B rows, 16B-aligned
        f32x4 o0 = *(const f32x4*)(os);
        f32x4 o1 = *(const f32x4*)(os + 4);
        f32x4 o2 = *(const f32x4*)(os + 8);
        f32x4 o3 = *(const f32x4*)(os + 12);
        f32x4 o4 = *(const f32x4*)(os + 16);
        f32x4 o5 = *(const f32x4*)(os + 20);
        f32x4 o6 = *(const f32x4*)(os + 24);
        float tors[6] = {o0[0], o0[1], o0[2], o0[3], o1[0], o1[1]};
        float j0[11] = {o1[2], o2[0], o2[2], o3[0], o3[2], o4[0], o4[2], o5[0], o5[2], o6[0], o6[2]};
        float j1[11] = {o1[3], o2[1], o2[3], o3[1], o3[3], o4[1], o4[3], o5[1], o5[3], o6[1], o6[3]};

        f32x2 y = *(const f32x2*)(b_in_t + fg * 2);
        #pragma unroll
        for (int t = 0; t < 6; ++t) {
            f32x2 ob = {tors[t], tors[t]};
            y = __builtin_elementwise_fma(ob, *(const f32x2*)(w_in_t + t * DD + fg * 2), y);
        }
        bf16x2 t2;
        t2[0] = (__bf16)tanh_fast(y[0]); t2[1] = (__bf16)tanh_fast(y[1]);
        *(bf16x2*)(wp) = t2;                          // node 0

        f32x2 wj0 = *(const f32x2*)(w_in_j + fg * 2);
        f32x2 wj1 = *(const f32x2*)(w_in_j + DD + fg * 2);
        f32x2 bj  = *(const f32x2*)(b_in_j + fg * 2);
        #pragma unroll
        for (int n = 1; n < NN; ++n) {
            f32x2 a0 = {j0[n - 1], j0[n - 1]};
            f32x2 a1 = {j1[n - 1], j1[n - 1]};
            f32x2 yn = __builtin_elementwise_fma(a1, wj1,
                        __builtin_elementwise_fma(a0, wj0, bj));
            t2[0] = (__bf16)tanh_fast(yn[0]); t2[1] = (__bf16)tanh_fast(yn[1]);
            *(bf16x2*)(wp + n * 128) = t2;            // stride 128B -> ds_write2_b32
        }
    }

    auto rdfrag = [&](const unsigned char* buf, int n, int ks) {
        return *(const bf16x8*)(buf + (el * NN + n) * 128 + ((ks * 64 + kg * 16) ^ swz));
    };

    f32x4 acc[NN];

    auto gcn_read = [&](const unsigned char* src, bf16x8 wf0, bf16x8 wf1) {
        #pragma unroll
        for (int n = 0; n < NN; ++n) {
            bf16x8 x0 = rdfrag(src, n, 0);
            bf16x8 x1 = rdfrag(src, n, 1);
            f32x4 a = {0.f, 0.f, 0.f, 0.f};
            a = MFMA(wf0, x0, a);
            a = MFMA(wf1, x1, a);
            acc[n] = a;
        }
    };
    auto gcn_write = [&](unsigned char* dst, f32x2 bv0, f32x2 bv1) {
        unsigned char* rowp = dst + (el * NN) * 128 + (((w * 16 + kg * 4) * 2) ^ swz);
        #pragma unroll
        for (int n = 0; n < NN; ++n) {
            f32x2 y0 = bv0, y1 = bv1;
            #pragma unroll
            for (int j = AC_OFF[n]; j < AC_OFF[n + 1]; ++j) {
                const float a = ac[j];
                f32x2 a2 = {a, a};
                const int m = AC_M[j];
                f32x2 lo = __builtin_shufflevector(acc[m], acc[m], 0, 1);
                f32x2 hi = __builtin_shufflevector(acc[m], acc[m], 2, 3);
                y0 = __builtin_elementwise_fma(a2, lo, y0);
                y1 = __builtin_elementwise_fma(a2, hi, y1);
            }
            bf16x4 o;
            o[0] = (__bf16)tanh_fast(y0[0]); o[1] = (__bf16)tanh_fast(y0[1]);
            o[2] = (__bf16)tanh_fast(y1[0]); o[3] = (__bf16)tanh_fast(y1[1]);
            *(bf16x4*)(rowp + n * 128) = o;           // stride 128B -> ds_write2_b64
        }
    };

    unsigned char* MYBUF = isP ? XP : X;     // wave-uniform select

    __syncthreads();                         // B1: X = x ready
    gcn_read(X, wfA0, wfA1);                 // R1: both groups read X
    __syncthreads();                         // B2: X fully read
    gcn_write(MYBUF, bA0, bA1);              // W1: p -> XP, v -> X (in place)
    __syncthreads();                         // B3: layer-1 outputs visible
    gcn_read(MYBUF, wfB0, wfB1);             // R2
    __syncthreads();                         // B4: buffers fully read
    gcn_write(MYBUF, bB0, bB1);              // W2: in place
    __syncthreads();                         // B5: xp2 in XP, xv2 in X

    // ---- heads, balanced: all 8 waves run policy units (0-3: nj 0..6, 4-7: nj 7..10);
    //      waves 4-7 additionally run the value head.
    {
        f32x4 bp  = *(const f32x4*)(b_pol1 + w * 16 + kg * 4);
        f32x4 wp2 = *(const f32x4*)(w_pol2 + w * 16 + kg * 4);
        bf16x8 pf0 = ldws(32 + w * 2 + 0);
        bf16x8 pf1 = ldws(32 + w * 2 + 1);
        auto pol_unit = [&](int nj) {
            bf16x8 x0 = rdfrag(XP, nj + 1, 0);
            bf16x8 x1 = rdfrag(XP, nj + 1, 1);
            f32x4 a = bp;
            a = MFMA(pf0, x0, a);
            a = MFMA(pf1, x1, a);
            float p = 0.f;
            #pragma unroll
            for (int r = 0; r < 4; ++r) p += tanh_fast(a[r]) * wp2[r];
            p += __shfl_xor(p, 16);
            p += __shfl_xor(p, 32);
            if (kg == 0) polp[w * 176 + nj * 16 + el] = p;
        };
        if (isP) {
            #pragma unroll
            for (int nj = 0; nj < 7; ++nj) pol_unit(nj);
        } else {
            #pragma unroll
            for (int nj = 7; nj < 11; ++nj) pol_unit(nj);
            // value head on X (= xv2)
            f32x4 a0 = *(const f32x4*)(b_val1 + w * 16 + kg * 4);
            f32x4 a1 = {0.f, 0.f, 0.f, 0.f};
            #pragma unroll 4
            for (int ks = 0; ks < 24; ks += 2) {
                bf16x8 wf0 = ldws(40 + w * 24 + ks);
                bf16x8 wf1 = ldws(40 + w * 24 + ks + 1);
                int n = ks >> 1;
                bf16x8 xf0 = rdfrag(X, n, 0);
                bf16x8 xf1 = rdfrag(X, n, 1);
                a0 = MFMA(wf0, xf0, a0);
                a1 = MFMA(wf1, xf1, a1);
            }
            f32x4 wv2 = *(const f32x4*)(w_val2 + w * 16 + kg * 4);
            float p = 0.f;
            #pragma unroll
            for (int r = 0; r < 4; ++r) p += tanh_fast(a0[r] + a1[r]) * wv2[r];
            p += __shfl_xor(p, 16);
            p += __shfl_xor(p, 32);
            if (kg == 0) valp[w * 16 + el] = p;
        }
    }
    __syncthreads();                         // B6: partials ready

    if (tid < 176) {
        int e2 = tid / 11, nj = tid - e2 * 11;
        out[(size_t)b0 * 11 + tid] =
            polp[nj * 16 + e2] + polp[176 + nj * 16 + e2] +
            polp[352 + nj * 16 + e2] + polp[528 + nj * 16 + e2] + b_pol2[0];
    }
    if (tid >= 192 && tid < 192 + EPB) {
        int e2 = tid - 192;
        out[(size_t)NB * 11 + b0 + e2] =
            valp[e2] + valp[16 + e2] + valp[32 + e2] + valp[48 + e2] + b_val2[0];
    }
}

extern "C" void kernel_launch(void* const* d_in, const int* in_sizes, int n_in,
                              void* d_out, int out_size, void* d_ws, size_t ws_size,
                              hipStream_t stream) {
    (void)in_sizes; (void)n_in; (void)out_size; (void)ws_size;
    const float** p = (const float**)d_in;
    __bf16* wsb = (__bf16*)d_ws;
    hipLaunchKernelGGL(prep_weights, dim3(34), dim3(256), 0, stream,
        p[6], p[8], p[10], p[12], p[14], p[18], wsb);
    hipLaunchKernelGGL(nervenet_mfma, dim3(NB / EPB), dim3(512), 0, stream,
        p[0], p[1], p[2], p[3], p[4], p[5],
        p[7], p[9], p[11], p[13],
        p[15], p[16], p[17],
        p[19], p[20], p[21],
        wsb, (float*)d_out);
}